// Round 1
// baseline (4860.737 us; speedup 1.0000x reference)
//
#include <hip/hip_runtime.h>
#include <hip/hip_bf16.h>
#include <math.h>

#define E_TOTAL 400000
#define ET 16          // edges per block
#define NTHREADS 256
#define NODE_D 120
#define XSTRIDE 121    // padded LDS stride for node features (bank-conflict-free)

__device__ __forceinline__ float silu_f(float x) { return x / (1.0f + __expf(-x)); }

__device__ __forceinline__ void gemm_chunk(const float* __restrict__ Wb, int KC,
                                           const float* __restrict__ P_lds,
                                           int wg, int eg, float4& accA, float4& accB) {
#pragma unroll 4
    for (int kc = 0; kc < KC; ++kc) {
        const float4 wv = ((const float4*)(Wb + kc * 128))[wg];
        const float2 pv = *(const float2*)(P_lds + kc * 16 + eg * 2);
        accA.x += pv.x * wv.x; accA.y += pv.x * wv.y; accA.z += pv.x * wv.z; accA.w += pv.x * wv.w;
        accB.x += pv.y * wv.x; accB.y += pv.y * wv.y; accB.z += pv.y * wv.z; accB.w += pv.y * wv.w;
    }
}

__global__ __launch_bounds__(NTHREADS) void fused_edge_kernel(
    const float* __restrict__ nodes, const int* __restrict__ edge_index,
    const int* __restrict__ graph_batch, const float* __restrict__ cell,
    const float* __restrict__ edge_shift, const float* __restrict__ pos,
    const float* __restrict__ W0, const float* __restrict__ W1, const float* __restrict__ W2,
    const float* __restrict__ ln_g, const float* __restrict__ ln_b,
    const float* __restrict__ df_w1, const float* __restrict__ df_b1,
    const float* __restrict__ df_w2, const float* __restrict__ df_b2,
    const float* __restrict__ mlp_w1, const float* __restrict__ mlp_b1,
    const float* __restrict__ mlp_w2, const float* __restrict__ mlp_b2,
    float* __restrict__ out)
{
    // LDS union (float offsets):
    //  [0,2048)        dfilter
    //  [2048,4096)     mixed (later regulated, in place)
    //  [4096,6032)     x1 (16x121)   -- aliases dembT[4096,5120)+sh1[5120,7168) used in earlier phases
    //  [6032,7968)     x2 (16x121)
    //  [7968,10016)    P chunk (128x16)
    __shared__ float smem[10016];
    __shared__ float dist_lds[ET];
    __shared__ int   src_lds[ET], dst_lds[ET];
    __shared__ float mu_lds[ET], rstd_lds[ET];
    __shared__ float wavered[4 * ET];

    float* dfilter_lds = smem;
    float* mixed_lds   = smem + 2048;
    float* x1_lds      = smem + 4096;
    float* x2_lds      = smem + 4096 + ET * XSTRIDE;
    float* P_lds       = smem + 4096 + 2 * ET * XSTRIDE;
    float* dembT_lds   = smem + 4096;        // dead before x1 load
    float* sh1_lds     = smem + 4096 + 1024; // dead before x load

    const int tid = threadIdx.x;
    const int e0g = blockIdx.x * ET;

    // ---- phase 0: geometry -> dist ----
    if (tid < ET) {
        const int e = e0g + tid;
        const int s = edge_index[e];
        const int d = edge_index[E_TOTAL + e];
        src_lds[tid] = s; dst_lds[tid] = d;
        const int g = graph_batch[s];
        const float* c = cell + g * 9;
        const float sx = edge_shift[e * 3 + 0], sy = edge_shift[e * 3 + 1], sz = edge_shift[e * 3 + 2];
        const float t0 = sx * c[0] + sy * c[3] + sz * c[6];
        const float t1 = sx * c[1] + sy * c[4] + sz * c[7];
        const float t2 = sx * c[2] + sy * c[5] + sz * c[8];
        const float r0 = pos[d * 3 + 0] - pos[s * 3 + 0] + t0;
        const float r1 = pos[d * 3 + 1] - pos[s * 3 + 1] + t1;
        const float r2 = pos[d * 3 + 2] - pos[s * 3 + 2] + t2;
        dist_lds[tid] = sqrtf(r0 * r0 + r1 * r1 + r2 * r2);
    }
    __syncthreads();

    // ---- phase 1: demb (transposed [k][e]) ----
    for (int i = tid; i < 64 * ET; i += NTHREADS) {
        const int k = i >> 4, e = i & 15;
        const float d = dist_lds[e];
        const float t = d - (7.0f / 63.0f) * (float)k;
        const float rbf = __expf(-40.5f * t * t);
        const float env = (d < 7.0f) ? (0.5f * (__cosf(d * (3.14159265358979f / 7.0f)) + 1.0f)) : 0.0f;
        dembT_lds[i] = rbf * env;
    }
    __syncthreads();

    // ---- phase 2: h1 = silu(demb @ df_w1 + b1) -> sh1[e][j] ----
    {
        const int j = tid & 127, eg2 = tid >> 7;
        float acc[8];
#pragma unroll
        for (int i = 0; i < 8; ++i) acc[i] = 0.0f;
        for (int k = 0; k < 64; ++k) {
            const float wv = df_w1[k * 128 + j];
            const float4 p0 = *(const float4*)(dembT_lds + k * 16 + eg2 * 8);
            const float4 p1 = *(const float4*)(dembT_lds + k * 16 + eg2 * 8 + 4);
            acc[0] += p0.x * wv; acc[1] += p0.y * wv; acc[2] += p0.z * wv; acc[3] += p0.w * wv;
            acc[4] += p1.x * wv; acc[5] += p1.y * wv; acc[6] += p1.z * wv; acc[7] += p1.w * wv;
        }
        const float b = df_b1[j];
#pragma unroll
        for (int i = 0; i < 8; ++i)
            sh1_lds[(eg2 * 8 + i) * 128 + j] = silu_f(acc[i] + b);
    }
    __syncthreads();

    // ---- phase 3: dfilter = sh1 @ df_w2 + b2 ----
    {
        const int e = tid >> 4, l = tid & 15;
        float acc[8];
#pragma unroll
        for (int i = 0; i < 8; ++i) acc[i] = 0.0f;
        for (int jj = 0; jj < 128; ++jj) {
            const float s = sh1_lds[e * 128 + jj];
            const float4* row = (const float4*)(df_w2 + jj * 128);
            const float4 wa = row[l * 2], wb = row[l * 2 + 1];
            acc[0] += s * wa.x; acc[1] += s * wa.y; acc[2] += s * wa.z; acc[3] += s * wa.w;
            acc[4] += s * wb.x; acc[5] += s * wb.y; acc[6] += s * wb.z; acc[7] += s * wb.w;
        }
#pragma unroll
        for (int i = 0; i < 8; ++i)
            dfilter_lds[e * 128 + l * 8 + i] = acc[i] + df_b2[l * 8 + i];
    }
    __syncthreads();

    // ---- phase 4: gather node features ----
    for (int i = tid; i < ET * 128; i += NTHREADS) {
        const int e = i >> 7, d = i & 127;
        if (d < NODE_D) {
            x1_lds[e * XSTRIDE + d] = nodes[src_lds[e] * NODE_D + d];
            x2_lds[e * XSTRIDE + d] = nodes[dst_lds[e] * NODE_D + d];
        }
    }
    __syncthreads();

    // ---- phase 5: tensor-product GEMM, K = 1024 + 256 + 64 in chunks of 128 ----
    const int wg = tid & 31, eg = tid >> 5;   // wg: 4 w-channels, eg: 2 edges
    float4 accA = make_float4(0, 0, 0, 0), accB = make_float4(0, 0, 0, 0);

    // segment 0: l0 pairs (32x32), P = a1[u]*a2[v]
    for (int c = 0; c < 8; ++c) {
        const int pbase = c * 128;
        for (int i = tid; i < 128 * ET; i += NTHREADS) {
            const int pl = i >> 4, e = i & 15;
            const int p = pbase + pl;
            const int u = p >> 5, v = p & 31;
            P_lds[i] = x1_lds[e * XSTRIDE + u] * x2_lds[e * XSTRIDE + v];
        }
        __syncthreads();
        gemm_chunk(W0 + pbase * 128, 128, P_lds, wg, eg, accA, accB);
        __syncthreads();
    }
    // segment 1: l1 pairs (16x16), P = sum_m b1[u][m]*b2[v][m] / sqrt(3)
    for (int c = 0; c < 2; ++c) {
        const int pbase = c * 128;
        for (int i = tid; i < 128 * ET; i += NTHREADS) {
            const int pl = i >> 4, e = i & 15;
            const int p = pbase + pl;
            const int u = p >> 4, v = p & 15;
            const float* a = x1_lds + e * XSTRIDE + 32 + u * 3;
            const float* b = x2_lds + e * XSTRIDE + 32 + v * 3;
            P_lds[i] = (a[0] * b[0] + a[1] * b[1] + a[2] * b[2]) * 0.57735026918962576f;
        }
        __syncthreads();
        gemm_chunk(W1 + pbase * 128, 128, P_lds, wg, eg, accA, accB);
        __syncthreads();
    }
    // segment 2: l2 pairs (8x8), P = sum_m c1[u][m]*c2[v][m] / sqrt(5)
    {
        for (int i = tid; i < 64 * ET; i += NTHREADS) {
            const int pl = i >> 4, e = i & 15;
            const int u = pl >> 3, v = pl & 7;
            const float* a = x1_lds + e * XSTRIDE + 80 + u * 5;
            const float* b = x2_lds + e * XSTRIDE + 80 + v * 5;
            P_lds[i] = (a[0] * b[0] + a[1] * b[1] + a[2] * b[2] + a[3] * b[3] + a[4] * b[4])
                       * 0.44721359549995794f;
        }
        __syncthreads();
        gemm_chunk(W2, 64, P_lds, wg, eg, accA, accB);
        __syncthreads();
    }

    // ---- phase 6: mixed = alpha * acc -> LDS ----
    {
        const float alpha = 0.027277236279f; // 1/sqrt(1344)
        float4 ma, mb;
        ma.x = accA.x * alpha; ma.y = accA.y * alpha; ma.z = accA.z * alpha; ma.w = accA.w * alpha;
        mb.x = accB.x * alpha; mb.y = accB.y * alpha; mb.z = accB.z * alpha; mb.w = accB.w * alpha;
        *(float4*)(mixed_lds + (eg * 2 + 0) * 128 + wg * 4) = ma;
        *(float4*)(mixed_lds + (eg * 2 + 1) * 128 + wg * 4) = mb;
    }
    __syncthreads();

    // ---- phase 7: LayerNorm stats ----
    {
        const int e = tid >> 4, l = tid & 15;
        const float4 m0 = *(const float4*)(mixed_lds + e * 128 + l * 8);
        const float4 m1 = *(const float4*)(mixed_lds + e * 128 + l * 8 + 4);
        float s1 = m0.x + m0.y + m0.z + m0.w + m1.x + m1.y + m1.z + m1.w;
        float s2 = m0.x * m0.x + m0.y * m0.y + m0.z * m0.z + m0.w * m0.w
                 + m1.x * m1.x + m1.y * m1.y + m1.z * m1.z + m1.w * m1.w;
#pragma unroll
        for (int off = 1; off < 16; off <<= 1) {
            s1 += __shfl_xor(s1, off);
            s2 += __shfl_xor(s2, off);
        }
        if (l == 0) {
            const float mu = s1 * (1.0f / 128.0f);
            const float var = s2 * (1.0f / 128.0f) - mu * mu;
            mu_lds[e] = mu;
            rstd_lds[e] = rsqrtf(var + 1e-5f);
        }
    }
    __syncthreads();

    // ---- phase 8: regulated = LN(mixed)*ln_g+ln_b, * dfilter (in place) ----
    for (int i = tid; i < ET * 128; i += NTHREADS) {
        const int e = i >> 7, w = i & 127;
        const float m = mixed_lds[i];
        const float r = (m - mu_lds[e]) * rstd_lds[e] * ln_g[w] + ln_b[w];
        mixed_lds[i] = r * dfilter_lds[i];
    }
    __syncthreads();

    // ---- phase 9: out = silu(reg @ mlp_w1 + b1) @ mlp_w2 + b2 ----
    {
        const int o = tid * 2;
        float acc0[16], acc1[16];
#pragma unroll
        for (int e = 0; e < 16; ++e) { acc0[e] = 0.0f; acc1[e] = 0.0f; }
        for (int w = 0; w < 128; ++w) {
            const float2 wv = *(const float2*)(mlp_w1 + w * 512 + o);
#pragma unroll
            for (int e = 0; e < 16; ++e) {
                const float r = mixed_lds[e * 128 + w];
                acc0[e] += r * wv.x;
                acc1[e] += r * wv.y;
            }
        }
        const float bb0 = mlp_b1[o], bb1 = mlp_b1[o + 1];
        const float w20 = mlp_w2[o], w21 = mlp_w2[o + 1];
        float po[16];
#pragma unroll
        for (int e = 0; e < 16; ++e)
            po[e] = silu_f(acc0[e] + bb0) * w20 + silu_f(acc1[e] + bb1) * w21;
#pragma unroll
        for (int off = 1; off < 64; off <<= 1) {
#pragma unroll
            for (int e = 0; e < 16; ++e) po[e] += __shfl_xor(po[e], off);
        }
        const int wid = tid >> 6;
#pragma unroll
        for (int jj = 0; jj < 16; ++jj)
            if ((tid & 63) == jj) wavered[wid * 16 + jj] = po[jj];
    }
    __syncthreads();
    if (tid < ET) {
        out[e0g + tid] = wavered[tid] + wavered[16 + tid] + wavered[32 + tid]
                       + wavered[48 + tid] + mlp_b2[0];
    }
}

extern "C" void kernel_launch(void* const* d_in, const int* in_sizes, int n_in,
                              void* d_out, int out_size, void* d_ws, size_t ws_size,
                              hipStream_t stream) {
    const float* nodes      = (const float*)d_in[0];
    const int*   edge_index = (const int*)  d_in[1];
    const int*   graph_b    = (const int*)  d_in[2];
    const float* cell       = (const float*)d_in[3];
    const float* edge_shift = (const float*)d_in[4];
    const float* pos        = (const float*)d_in[5];
    const float* W0         = (const float*)d_in[6];
    const float* W1         = (const float*)d_in[7];
    const float* W2         = (const float*)d_in[8];
    const float* ln_g       = (const float*)d_in[9];
    const float* ln_b       = (const float*)d_in[10];
    const float* df_w1      = (const float*)d_in[11];
    const float* df_b1      = (const float*)d_in[12];
    const float* df_w2      = (const float*)d_in[13];
    const float* df_b2      = (const float*)d_in[14];
    const float* mlp_w1     = (const float*)d_in[15];
    const float* mlp_b1     = (const float*)d_in[16];
    const float* mlp_w2     = (const float*)d_in[17];
    const float* mlp_b2     = (const float*)d_in[18];
    float* out = (float*)d_out;

    const int E = in_sizes[1] / 2;            // 400000
    const int grid = E / ET;                  // 25000 (E divisible by 16)

    hipLaunchKernelGGL(fused_edge_kernel, dim3(grid), dim3(NTHREADS), 0, stream,
                       nodes, edge_index, graph_b, cell, edge_shift, pos,
                       W0, W1, W2, ln_g, ln_b, df_w1, df_b1, df_w2, df_b2,
                       mlp_w1, mlp_b1, mlp_w2, mlp_b2, out);
}

// Round 2
// 536.161 us; speedup vs baseline: 9.0658x; 9.0658x over previous
//
#include <hip/hip_runtime.h>
#include <hip/hip_bf16.h>
#include <math.h>

typedef unsigned short ushort_t;
typedef short short8 __attribute__((ext_vector_type(8)));
typedef short short4v __attribute__((ext_vector_type(4)));
typedef float f32x4 __attribute__((ext_vector_type(4)));

#define E_TOTAL 400000
#define ET 32          // edges per block
#define NTHR 512       // 8 waves
#define NODE_D 120
#define XSTR 124       // fp32 node-feature LDS stride (16B-aligned rows)
#define PSTR 520       // bf16 P-chunk LDS stride (1040B rows: 16B-aligned, bank-step 4)
#define HSTR 136       // bf16 h1/reg LDS stride (272B rows)
#define DSTR 72        // bf16 demb LDS stride (144B rows)

#define ALPHA 0.0272772362793f   // 1/sqrt(1344)
#define S_L1  0.57735026918962f  // 1/sqrt(3)
#define S_L2  0.44721359549996f  // 1/sqrt(5)

// ws layout (ushort elements): TP W-frags [0,172032), df_w1 [172032,180224),
// df_w2 [180224,196608), mlp_w1 [196608,262144).  B-frag order:
// idx = ((kt*NT + nt)*64 + lane)*8 + jj  with k = kt*32 + 8*(lane>>4) + jj,
// n = nt*16 + (lane&15).
#define WS_WF1 172032
#define WS_WF2 180224
#define WS_WM1 196608
#define WS_TOTAL 262144

__device__ __forceinline__ ushort_t f2b(float f) {
    unsigned int b = __float_as_uint(f);
    b += 0x7FFFu + ((b >> 16) & 1u);   // RNE
    return (ushort_t)(b >> 16);
}
__device__ __forceinline__ float silu_f(float x) { return x / (1.0f + __expf(-x)); }

__global__ __launch_bounds__(256) void prep_weights(
    const float* __restrict__ W0, const float* __restrict__ W1, const float* __restrict__ W2,
    const float* __restrict__ df_w1, const float* __restrict__ df_w2,
    const float* __restrict__ mlp_w1, ushort_t* __restrict__ ws)
{
    const int i = blockIdx.x * 256 + threadIdx.x;
    if (i >= WS_TOTAL) return;
    float v;
    if (i < WS_WF1) {            // TP: 42 kt x 8 nt
        const int r = i;
        const int kt = r >> 12, nt = (r >> 9) & 7, l = (r >> 3) & 63, jj = r & 7;
        const int k = kt * 32 + ((l >> 4) << 3) + jj;
        const int n = nt * 16 + (l & 15);
        if (k < 1024)      v = W0[k * 128 + n] * ALPHA;
        else if (k < 1280) v = W1[(k - 1024) * 128 + n] * (ALPHA * S_L1);
        else               v = W2[(k - 1280) * 128 + n] * (ALPHA * S_L2);
    } else if (i < WS_WF2) {     // df_w1: 2 kt x 8 nt
        const int r = i - WS_WF1;
        const int kt = r >> 12, nt = (r >> 9) & 7, l = (r >> 3) & 63, jj = r & 7;
        v = df_w1[(kt * 32 + ((l >> 4) << 3) + jj) * 128 + nt * 16 + (l & 15)];
    } else if (i < WS_WM1) {     // df_w2: 4 kt x 8 nt
        const int r = i - WS_WF2;
        const int kt = r >> 12, nt = (r >> 9) & 7, l = (r >> 3) & 63, jj = r & 7;
        v = df_w2[(kt * 32 + ((l >> 4) << 3) + jj) * 128 + nt * 16 + (l & 15)];
    } else {                     // mlp_w1: 4 kt x 32 nt
        const int r = i - WS_WM1;
        const int kt = r >> 14, nt = (r >> 9) & 31, l = (r >> 3) & 63, jj = r & 7;
        v = mlp_w1[(kt * 32 + ((l >> 4) << 3) + jj) * 512 + nt * 16 + (l & 15)];
    }
    ws[i] = f2b(v);
}

__device__ __forceinline__ void build_l0(ushort_t* __restrict__ P,
                                         const float* __restrict__ x1,
                                         const float* __restrict__ x2,
                                         int tid, int ubase)
{
    const int e = tid >> 4, uu = tid & 15;
    const float a1u = x1[e * XSTR + ubase + uu];
    f32x4 a2v[8];
#pragma unroll
    for (int q = 0; q < 8; ++q) a2v[q] = *(const f32x4*)(x2 + e * XSTR + q * 4);
    ushort_t tmp[32];
#pragma unroll
    for (int q = 0; q < 8; ++q) {
        tmp[q * 4 + 0] = f2b(a1u * a2v[q][0]);
        tmp[q * 4 + 1] = f2b(a1u * a2v[q][1]);
        tmp[q * 4 + 2] = f2b(a1u * a2v[q][2]);
        tmp[q * 4 + 3] = f2b(a1u * a2v[q][3]);
    }
    ushort_t* dst = P + e * PSTR + uu * 32;
#pragma unroll
    for (int q = 0; q < 4; ++q)
        *(short8*)(dst + q * 8) = *(const short8*)(tmp + q * 8);
}

__global__ __launch_bounds__(NTHR, 4) void fused_edge_kernel(
    const float* __restrict__ nodes, const int* __restrict__ edge_index,
    const int* __restrict__ graph_batch, const float* __restrict__ cell,
    const float* __restrict__ edge_shift, const float* __restrict__ pos,
    const float* __restrict__ ln_g, const float* __restrict__ ln_b,
    const float* __restrict__ df_b1, const float* __restrict__ df_b2,
    const float* __restrict__ mlp_b1, const float* __restrict__ mlp_w2,
    const float* __restrict__ mlp_b2,
    const ushort_t* __restrict__ wsp, float* __restrict__ out)
{
    __shared__ __align__(16) ushort_t P[ET * PSTR];       // 33280 B
    __shared__ __align__(16) float xbuf[2 * ET * XSTR];   // 31744 B (aliased later)
    __shared__ __align__(16) ushort_t demb[ET * DSTR];    // 4608 B
    __shared__ float dist_s[ET];
    __shared__ int sidx[ET], didx[ET];
    __shared__ float mu_s[ET], rstd_s[ET];

    float* x1 = xbuf;
    float* x2 = xbuf + ET * XSTR;
    // aliases into xbuf (x dead after P chunk-C build):
    ushort_t* h1   = (ushort_t*)xbuf;                       // [0, 8704) B
    ushort_t* regb = (ushort_t*)xbuf + ET * HSTR;           // [8704, 17408) B
    float* red1 = (float*)((char*)xbuf + 17408);            // 512 floats (s1, s2)
    float* red2 = (float*)((char*)xbuf + 19456);            // 256 floats

    const int tid = threadIdx.x;
    const int e0g = blockIdx.x * ET;
    const int wave = tid >> 6, lane = tid & 63;
    const int lr = lane & 15, lg = lane >> 4;

    // ---- phase 0: geometry ----
    if (tid < ET) {
        const int e = e0g + tid;
        const int s = edge_index[e];
        const int d = edge_index[E_TOTAL + e];
        sidx[tid] = s; didx[tid] = d;
        const int g = graph_batch[s];
        const float* c = cell + g * 9;
        const float sx = edge_shift[e * 3], sy = edge_shift[e * 3 + 1], sz = edge_shift[e * 3 + 2];
        const float t0 = sx * c[0] + sy * c[3] + sz * c[6];
        const float t1 = sx * c[1] + sy * c[4] + sz * c[7];
        const float t2 = sx * c[2] + sy * c[5] + sz * c[8];
        const float r0 = pos[d * 3 + 0] - pos[s * 3 + 0] + t0;
        const float r1 = pos[d * 3 + 1] - pos[s * 3 + 1] + t1;
        const float r2 = pos[d * 3 + 2] - pos[s * 3 + 2] + t2;
        dist_s[tid] = sqrtf(r0 * r0 + r1 * r1 + r2 * r2);
    }
    __syncthreads();

    // ---- phase 1: gather x1/x2 + demb build ----
    for (int i = tid; i < ET * 32; i += NTHR) {
        const int e = i >> 5, c = i & 31;
        if (c < 30)
            *(float4*)(x1 + e * XSTR + c * 4) = *(const float4*)(nodes + (size_t)sidx[e] * NODE_D + c * 4);
    }
    for (int i = tid; i < ET * 32; i += NTHR) {
        const int e = i >> 5, c = i & 31;
        if (c < 30)
            *(float4*)(x2 + e * XSTR + c * 4) = *(const float4*)(nodes + (size_t)didx[e] * NODE_D + c * 4);
    }
    for (int i = tid; i < ET * 64; i += NTHR) {
        const int e = i >> 6, k = i & 63;
        const float d = dist_s[e];
        const float t = d - (7.0f / 63.0f) * (float)k;
        const float rbf = __expf(-40.5f * t * t);
        const float env = (d < 7.0f) ? (0.5f * (__cosf(d * (3.14159265358979f / 7.0f)) + 1.0f)) : 0.0f;
        demb[e * DSTR + k] = f2b(rbf * env);
    }
    __syncthreads();

    const char* pA0 = (const char*)P + lr * (PSTR * 2) + lg * 16;
    const char* pA1 = pA0 + 16 * (PSTR * 2);
    const short8* WT8 = (const short8*)wsp;
    const int bcol = wave * 64 + lane;

    f32x4 acc0 = {0.f, 0.f, 0.f, 0.f}, acc1 = {0.f, 0.f, 0.f, 0.f};

    // ---- TP chunk A: k 0..511 (l0, u 0..15) ----
    build_l0(P, x1, x2, tid, 0);
    __syncthreads();
#pragma unroll 4
    for (int kt = 0; kt < 16; ++kt) {
        const short8 a0 = *(const short8*)(pA0 + kt * 64);
        const short8 a1 = *(const short8*)(pA1 + kt * 64);
        const short8 b = WT8[kt * 512 + bcol];
        acc0 = __builtin_amdgcn_mfma_f32_16x16x32_bf16(a0, b, acc0, 0, 0, 0);
        acc1 = __builtin_amdgcn_mfma_f32_16x16x32_bf16(a1, b, acc1, 0, 0, 0);
    }
    __syncthreads();

    // ---- TP chunk B: k 512..1023 (l0, u 16..31) ----
    build_l0(P, x1, x2, tid, 16);
    __syncthreads();
#pragma unroll 4
    for (int kt = 0; kt < 16; ++kt) {
        const short8 a0 = *(const short8*)(pA0 + kt * 64);
        const short8 a1 = *(const short8*)(pA1 + kt * 64);
        const short8 b = WT8[(16 + kt) * 512 + bcol];
        acc0 = __builtin_amdgcn_mfma_f32_16x16x32_bf16(a0, b, acc0, 0, 0, 0);
        acc1 = __builtin_amdgcn_mfma_f32_16x16x32_bf16(a1, b, acc1, 0, 0, 0);
    }
    __syncthreads();

    // ---- TP chunk C build: k 1024..1343 (l1 256 + l2 64) ----
    {
        const int e = tid >> 4, t = tid & 15;
        const float* b1p = x1 + e * XSTR + 32 + 3 * t;
        const float b1a = b1p[0], b1b = b1p[1], b1c = b1p[2];
        ushort_t tmp[16];
#pragma unroll
        for (int v = 0; v < 16; ++v) {
            const float* b2p = x2 + e * XSTR + 32 + 3 * v;
            tmp[v] = f2b(b1a * b2p[0] + b1b * b2p[1] + b1c * b2p[2]);
        }
        ushort_t* dst = P + e * PSTR + t * 16;
        *(short8*)(dst)     = *(const short8*)(tmp);
        *(short8*)(dst + 8) = *(const short8*)(tmp + 8);
        ushort_t t2[4];
#pragma unroll
        for (int q = 0; q < 4; ++q) {
            const int p = 4 * t + q, u = p >> 3, v = p & 7;
            const float* c1p = x1 + e * XSTR + 80 + 5 * u;
            const float* c2p = x2 + e * XSTR + 80 + 5 * v;
            t2[q] = f2b(c1p[0] * c2p[0] + c1p[1] * c2p[1] + c1p[2] * c2p[2]
                      + c1p[3] * c2p[3] + c1p[4] * c2p[4]);
        }
        *(short4v*)(P + e * PSTR + 256 + t * 4) = *(const short4v*)(t2);
    }
    __syncthreads();

    // ---- TP chunk C gemm + filter GEMM1 (x region now dead except via h1 write) ----
#pragma unroll 2
    for (int kt = 0; kt < 10; ++kt) {
        const short8 a0 = *(const short8*)(pA0 + kt * 64);
        const short8 a1 = *(const short8*)(pA1 + kt * 64);
        const short8 b = WT8[(32 + kt) * 512 + bcol];
        acc0 = __builtin_amdgcn_mfma_f32_16x16x32_bf16(a0, b, acc0, 0, 0, 0);
        acc1 = __builtin_amdgcn_mfma_f32_16x16x32_bf16(a1, b, acc1, 0, 0, 0);
    }
    {
        f32x4 f0 = {0.f, 0.f, 0.f, 0.f}, f1 = {0.f, 0.f, 0.f, 0.f};
        const char* dA0 = (const char*)demb + lr * (DSTR * 2) + lg * 16;
        const char* dA1 = dA0 + 16 * (DSTR * 2);
#pragma unroll
        for (int kt = 0; kt < 2; ++kt) {
            const short8 a0 = *(const short8*)(dA0 + kt * 64);
            const short8 a1 = *(const short8*)(dA1 + kt * 64);
            const short8 b = WT8[WS_WF1 / 8 + kt * 512 + bcol];
            f0 = __builtin_amdgcn_mfma_f32_16x16x32_bf16(a0, b, f0, 0, 0, 0);
            f1 = __builtin_amdgcn_mfma_f32_16x16x32_bf16(a1, b, f1, 0, 0, 0);
        }
        const int n = wave * 16 + lr;
        const float bb = df_b1[n];
#pragma unroll
        for (int r = 0; r < 4; ++r) {
            h1[(lg * 4 + r) * HSTR + n]        = f2b(silu_f(f0[r] + bb));
            h1[(16 + lg * 4 + r) * HSTR + n]   = f2b(silu_f(f1[r] + bb));
        }
    }
    __syncthreads();

    // ---- filter GEMM2 -> dfilter (regs) ----
    f32x4 d0 = {0.f, 0.f, 0.f, 0.f}, d1 = {0.f, 0.f, 0.f, 0.f};
    {
        const char* hA0 = (const char*)h1 + lr * (HSTR * 2) + lg * 16;
        const char* hA1 = hA0 + 16 * (HSTR * 2);
#pragma unroll
        for (int kt = 0; kt < 4; ++kt) {
            const short8 a0 = *(const short8*)(hA0 + kt * 64);
            const short8 a1 = *(const short8*)(hA1 + kt * 64);
            const short8 b = WT8[WS_WF2 / 8 + kt * 512 + bcol];
            d0 = __builtin_amdgcn_mfma_f32_16x16x32_bf16(a0, b, d0, 0, 0, 0);
            d1 = __builtin_amdgcn_mfma_f32_16x16x32_bf16(a1, b, d1, 0, 0, 0);
        }
        const int n = wave * 16 + lr;
        const float b2v = df_b2[n];
#pragma unroll
        for (int r = 0; r < 4; ++r) { d0[r] += b2v; d1[r] += b2v; }
    }

    // ---- LayerNorm partials (mixed is final in acc0/acc1) ----
#pragma unroll
    for (int mt = 0; mt < 2; ++mt) {
#pragma unroll
        for (int r = 0; r < 4; ++r) {
            const float v = mt ? acc1[r] : acc0[r];
            float s1 = v, s2 = v * v;
            s1 += __shfl_xor(s1, 1);  s2 += __shfl_xor(s2, 1);
            s1 += __shfl_xor(s1, 2);  s2 += __shfl_xor(s2, 2);
            s1 += __shfl_xor(s1, 4);  s2 += __shfl_xor(s2, 4);
            s1 += __shfl_xor(s1, 8);  s2 += __shfl_xor(s2, 8);
            if (lr == 0) {
                const int idx = ((wave * 2 + mt) * 4 + lg) * 4 + r;
                red1[idx] = s1;
                red1[256 + idx] = s2;
            }
        }
    }
    __syncthreads();
    if (tid < ET) {
        const int mt = tid >> 4, g = (tid >> 2) & 3, r = tid & 3;
        float s1 = 0.f, s2 = 0.f;
#pragma unroll
        for (int w = 0; w < 8; ++w) {
            const int idx = ((w * 2 + mt) * 4 + g) * 4 + r;
            s1 += red1[idx];
            s2 += red1[256 + idx];
        }
        const float mu = s1 * (1.0f / 128.0f);
        const float var = s2 * (1.0f / 128.0f) - mu * mu;
        mu_s[tid] = mu;
        rstd_s[tid] = rsqrtf(var + 1e-5f);
    }
    __syncthreads();

    // ---- regulated -> bf16 LDS ----
    {
        const int n = wave * 16 + lr;
        const float gv = ln_g[n], bv = ln_b[n];
#pragma unroll
        for (int mt = 0; mt < 2; ++mt) {
#pragma unroll
            for (int r = 0; r < 4; ++r) {
                const int row = mt * 16 + lg * 4 + r;
                const float v = mt ? acc1[r] : acc0[r];
                const float ln = (v - mu_s[row]) * rstd_s[row] * gv + bv;
                const float df = mt ? d1[r] : d0[r];
                regb[row * HSTR + n] = f2b(ln * df);
            }
        }
    }
    __syncthreads();

    // ---- MLP: out = silu(reg @ w1 + b1) @ w2 + b2 ----
    {
        f32x4 m00 = {0.f,0.f,0.f,0.f}, m01 = {0.f,0.f,0.f,0.f};
        f32x4 m10 = {0.f,0.f,0.f,0.f}, m11 = {0.f,0.f,0.f,0.f};
        f32x4 m20 = {0.f,0.f,0.f,0.f}, m21 = {0.f,0.f,0.f,0.f};
        f32x4 m30 = {0.f,0.f,0.f,0.f}, m31 = {0.f,0.f,0.f,0.f};
        const char* rA0 = (const char*)regb + lr * (HSTR * 2) + lg * 16;
        const char* rA1 = rA0 + 16 * (HSTR * 2);
#pragma unroll
        for (int kt = 0; kt < 4; ++kt) {
            const short8 a0 = *(const short8*)(rA0 + kt * 64);
            const short8 a1 = *(const short8*)(rA1 + kt * 64);
            const int base = WS_WM1 / 8 + kt * 2048 + wave * 256 + lane;
            const short8 b0 = WT8[base];
            const short8 b1 = WT8[base + 64];
            const short8 b2 = WT8[base + 128];
            const short8 b3 = WT8[base + 192];
            m00 = __builtin_amdgcn_mfma_f32_16x16x32_bf16(a0, b0, m00, 0, 0, 0);
            m01 = __builtin_amdgcn_mfma_f32_16x16x32_bf16(a1, b0, m01, 0, 0, 0);
            m10 = __builtin_amdgcn_mfma_f32_16x16x32_bf16(a0, b1, m10, 0, 0, 0);
            m11 = __builtin_amdgcn_mfma_f32_16x16x32_bf16(a1, b1, m11, 0, 0, 0);
            m20 = __builtin_amdgcn_mfma_f32_16x16x32_bf16(a0, b2, m20, 0, 0, 0);
            m21 = __builtin_amdgcn_mfma_f32_16x16x32_bf16(a1, b2, m21, 0, 0, 0);
            m30 = __builtin_amdgcn_mfma_f32_16x16x32_bf16(a0, b3, m30, 0, 0, 0);
            m31 = __builtin_amdgcn_mfma_f32_16x16x32_bf16(a1, b3, m31, 0, 0, 0);
        }
        float po0[4] = {0.f,0.f,0.f,0.f}, po1[4] = {0.f,0.f,0.f,0.f};
#pragma unroll
        for (int q = 0; q < 4; ++q) {
            const int n = (wave * 4 + q) * 16 + lr;
            const float b1v = mlp_b1[n];
            const float w2v = mlp_w2[n];
            const f32x4 h0 = (q == 0) ? m00 : (q == 1) ? m10 : (q == 2) ? m20 : m30;
            const f32x4 h1v = (q == 0) ? m01 : (q == 1) ? m11 : (q == 2) ? m21 : m31;
#pragma unroll
            for (int r = 0; r < 4; ++r) {
                po0[r] += silu_f(h0[r] + b1v) * w2v;
                po1[r] += silu_f(h1v[r] + b1v) * w2v;
            }
        }
#pragma unroll
        for (int r = 0; r < 4; ++r) {
            float a = po0[r], b = po1[r];
            a += __shfl_xor(a, 1); b += __shfl_xor(b, 1);
            a += __shfl_xor(a, 2); b += __shfl_xor(b, 2);
            a += __shfl_xor(a, 4); b += __shfl_xor(b, 4);
            a += __shfl_xor(a, 8); b += __shfl_xor(b, 8);
            if (lr == 0) {
                red2[((wave * 2 + 0) * 4 + lg) * 4 + r] = a;
                red2[((wave * 2 + 1) * 4 + lg) * 4 + r] = b;
            }
        }
    }
    __syncthreads();
    if (tid < ET) {
        const int mt = tid >> 4, g = (tid >> 2) & 3, r = tid & 3;
        float s = 0.f;
#pragma unroll
        for (int w = 0; w < 8; ++w)
            s += red2[((w * 2 + mt) * 4 + g) * 4 + r];
        out[e0g + tid] = s + mlp_b2[0];
    }
}

extern "C" void kernel_launch(void* const* d_in, const int* in_sizes, int n_in,
                              void* d_out, int out_size, void* d_ws, size_t ws_size,
                              hipStream_t stream) {
    const float* nodes      = (const float*)d_in[0];
    const int*   edge_index = (const int*)  d_in[1];
    const int*   graph_b    = (const int*)  d_in[2];
    const float* cell       = (const float*)d_in[3];
    const float* edge_shift = (const float*)d_in[4];
    const float* pos        = (const float*)d_in[5];
    const float* W0         = (const float*)d_in[6];
    const float* W1         = (const float*)d_in[7];
    const float* W2         = (const float*)d_in[8];
    const float* ln_g       = (const float*)d_in[9];
    const float* ln_b       = (const float*)d_in[10];
    const float* df_w1      = (const float*)d_in[11];
    const float* df_b1      = (const float*)d_in[12];
    const float* df_w2      = (const float*)d_in[13];
    const float* df_b2      = (const float*)d_in[14];
    const float* mlp_w1     = (const float*)d_in[15];
    const float* mlp_b1     = (const float*)d_in[16];
    const float* mlp_w2     = (const float*)d_in[17];
    const float* mlp_b2     = (const float*)d_in[18];
    float* out = (float*)d_out;
    ushort_t* ws = (ushort_t*)d_ws;

    hipLaunchKernelGGL(prep_weights, dim3((WS_TOTAL + 255) / 256), dim3(256), 0, stream,
                       W0, W1, W2, df_w1, df_w2, mlp_w1, ws);

    const int E = in_sizes[1] / 2;
    const int grid = E / ET;   // 12500
    hipLaunchKernelGGL(fused_edge_kernel, dim3(grid), dim3(NTHR), 0, stream,
                       nodes, edge_index, graph_b, cell, edge_shift, pos,
                       ln_g, ln_b, df_b1, df_b2, mlp_b1, mlp_w2, mlp_b2,
                       ws, out);
}

// Round 3
// 509.394 us; speedup vs baseline: 9.5422x; 1.0525x over previous
//
#include <hip/hip_runtime.h>
#include <hip/hip_bf16.h>
#include <math.h>

typedef unsigned short ushort_t;
typedef short short8 __attribute__((ext_vector_type(8)));
typedef float f32x4 __attribute__((ext_vector_type(4)));

#define E_TOTAL 400000
#define ET 32          // edges per block
#define NTHR 512       // 8 waves
#define NODE_D 120
#define XSTR 124       // fp32 node-feature LDS stride

#define ALPHA 0.0272772362793f   // 1/sqrt(1344)
#define S_L1  0.57735026918962f  // 1/sqrt(3)
#define S_L2  0.44721359549996f  // 1/sqrt(5)

// ws layout (ushort elements): TP W-frags [0,172032), df_w1 [172032,180224),
// df_w2 [180224,196608), mlp_w1 [196608,262144).  B-frag order:
// idx = ((kt*NT + nt)*64 + lane)*8 + jj  with k = kt*32 + 8*(lane>>4) + jj,
// n = nt*16 + (lane&15).
#define WS_WF1 172032
#define WS_WF2 180224
#define WS_WM1 196608
#define WS_TOTAL 262144

__device__ __forceinline__ ushort_t f2b(float f) {
    unsigned int b = __float_as_uint(f);
    b += 0x7FFFu + ((b >> 16) & 1u);   // RNE
    return (ushort_t)(b >> 16);
}
__device__ __forceinline__ unsigned int f2b2(float a, float b) {
    __hip_bfloat162 h = __float22bfloat162_rn(make_float2(a, b));  // v_cvt_pk_bf16_f32
    union { __hip_bfloat162 h2; unsigned int u; } cv; cv.h2 = h;
    return cv.u;
}
__device__ __forceinline__ float silu_f(float x) { return x / (1.0f + __expf(-x)); }

__global__ __launch_bounds__(256) void prep_weights(
    const float* __restrict__ W0, const float* __restrict__ W1, const float* __restrict__ W2,
    const float* __restrict__ df_w1, const float* __restrict__ df_w2,
    const float* __restrict__ mlp_w1, ushort_t* __restrict__ ws)
{
    const int i = blockIdx.x * 256 + threadIdx.x;
    if (i >= WS_TOTAL) return;
    float v;
    if (i < WS_WF1) {            // TP: 42 kt x 8 nt
        const int r = i;
        const int kt = r >> 12, nt = (r >> 9) & 7, l = (r >> 3) & 63, jj = r & 7;
        const int k = kt * 32 + ((l >> 4) << 3) + jj;
        const int n = nt * 16 + (l & 15);
        if (k < 1024)      v = W0[k * 128 + n] * ALPHA;
        else if (k < 1280) v = W1[(k - 1024) * 128 + n] * (ALPHA * S_L1);
        else               v = W2[(k - 1280) * 128 + n] * (ALPHA * S_L2);
    } else if (i < WS_WF2) {     // df_w1: 2 kt x 8 nt
        const int r = i - WS_WF1;
        const int kt = r >> 12, nt = (r >> 9) & 7, l = (r >> 3) & 63, jj = r & 7;
        v = df_w1[(kt * 32 + ((l >> 4) << 3) + jj) * 128 + nt * 16 + (l & 15)];
    } else if (i < WS_WM1) {     // df_w2: 4 kt x 8 nt
        const int r = i - WS_WF2;
        const int kt = r >> 12, nt = (r >> 9) & 7, l = (r >> 3) & 63, jj = r & 7;
        v = df_w2[(kt * 32 + ((l >> 4) << 3) + jj) * 128 + nt * 16 + (l & 15)];
    } else {                     // mlp_w1: 4 kt x 32 nt
        const int r = i - WS_WM1;
        const int kt = r >> 14, nt = (r >> 9) & 31, l = (r >> 3) & 63, jj = r & 7;
        v = mlp_w1[(kt * 32 + ((l >> 4) << 3) + jj) * 512 + nt * 16 + (l & 15)];
    }
    ws[i] = f2b(v);
}

// Build l0 P products directly in A-fragment-linear layout.
// Pf slot = (ktl*2 + half)*64 + lane, 8 ushort each; lane = kg*16 + er.
// Element (k = ktl*32 + kg*8 + jj, edge = half*16 + er).
__device__ __forceinline__ void build_l0_frag(ushort_t* __restrict__ Pf,
                                              const float* __restrict__ x1,
                                              const float* __restrict__ x2,
                                              int tid, int ubase)
{
    const int er = tid & 15, kg = (tid >> 4) & 3, w = tid >> 6;
#pragma unroll
    for (int half = 0; half < 2; ++half) {
        const int e = half * 16 + er;
        const float* x2r = x2 + e * XSTR + kg * 8;
        const float2 xv0 = *(const float2*)(x2r + 0);
        const float2 xv1 = *(const float2*)(x2r + 2);
        const float2 xv2 = *(const float2*)(x2r + 4);
        const float2 xv3 = *(const float2*)(x2r + 6);
#pragma unroll
        for (int uu = 0; uu < 2; ++uu) {
            const int ul = w + uu * 8;                 // local kt
            const float a1 = x1[e * XSTR + ubase + ul];
            uint4 o;
            o.x = f2b2(a1 * xv0.x, a1 * xv0.y);
            o.y = f2b2(a1 * xv1.x, a1 * xv1.y);
            o.z = f2b2(a1 * xv2.x, a1 * xv2.y);
            o.w = f2b2(a1 * xv3.x, a1 * xv3.y);
            *(uint4*)(Pf + ((ul * 2 + half) * 64 + kg * 16 + er) * 8) = o;
        }
    }
}

__global__ __launch_bounds__(NTHR, 4) void fused_edge_kernel(
    const float* __restrict__ nodes, const int* __restrict__ edge_index,
    const int* __restrict__ graph_batch, const float* __restrict__ cell,
    const float* __restrict__ edge_shift, const float* __restrict__ pos,
    const float* __restrict__ ln_g, const float* __restrict__ ln_b,
    const float* __restrict__ df_b1, const float* __restrict__ df_b2,
    const float* __restrict__ mlp_b1, const float* __restrict__ mlp_w2,
    const float* __restrict__ mlp_b2,
    const ushort_t* __restrict__ wsp, float* __restrict__ out)
{
    __shared__ __align__(16) ushort_t Pf[16 * 2 * 64 * 8];   // 32 KB, fragment-linear
    __shared__ __align__(16) float xbuf[2 * ET * XSTR];      // 31.75 KB (aliased later)
    __shared__ __align__(16) ushort_t dembF[2 * 2 * 64 * 8]; // 4 KB, fragment-linear
    __shared__ float dist_s[ET];
    __shared__ int sidx[ET], didx[ET];
    __shared__ float mu_s[ET], rstd_s[ET];

    float* x1 = xbuf;
    float* x2 = xbuf + ET * XSTR;
    // aliases into xbuf (x dead after chunk-C build):
    ushort_t* h1F  = (ushort_t*)xbuf;                 // 4 kt*2*64*8 = 4096 us = 8 KB
    ushort_t* regF = (ushort_t*)xbuf + 4096;          // 8 KB
    float* red1 = (float*)((char*)xbuf + 16384);      // 512 floats
    float* red2 = (float*)((char*)xbuf + 18432);      // 256 floats

    const int tid = threadIdx.x;
    const int e0g = blockIdx.x * ET;
    const int wave = tid >> 6, lane = tid & 63;
    const int lr = lane & 15, lg = lane >> 4;

    // ---- phase 0: geometry ----
    if (tid < ET) {
        const int e = e0g + tid;
        const int s = edge_index[e];
        const int d = edge_index[E_TOTAL + e];
        sidx[tid] = s; didx[tid] = d;
        const int g = graph_batch[s];
        const float* c = cell + g * 9;
        const float sx = edge_shift[e * 3], sy = edge_shift[e * 3 + 1], sz = edge_shift[e * 3 + 2];
        const float t0 = sx * c[0] + sy * c[3] + sz * c[6];
        const float t1 = sx * c[1] + sy * c[4] + sz * c[7];
        const float t2 = sx * c[2] + sy * c[5] + sz * c[8];
        const float r0 = pos[d * 3 + 0] - pos[s * 3 + 0] + t0;
        const float r1 = pos[d * 3 + 1] - pos[s * 3 + 1] + t1;
        const float r2 = pos[d * 3 + 2] - pos[s * 3 + 2] + t2;
        dist_s[tid] = sqrtf(r0 * r0 + r1 * r1 + r2 * r2);
    }
    __syncthreads();

    // ---- phase 1: gather x1/x2 + demb build (fragment-linear) ----
    for (int i = tid; i < ET * 32; i += NTHR) {
        const int e = i >> 5, c = i & 31;
        if (c < 30)
            *(float4*)(x1 + e * XSTR + c * 4) = *(const float4*)(nodes + (size_t)sidx[e] * NODE_D + c * 4);
    }
    for (int i = tid; i < ET * 32; i += NTHR) {
        const int e = i >> 5, c = i & 31;
        if (c < 30)
            *(float4*)(x2 + e * XSTR + c * 4) = *(const float4*)(nodes + (size_t)didx[e] * NODE_D + c * 4);
    }
    for (int i = tid; i < ET * 64; i += NTHR) {
        const int e = i >> 6, k = i & 63;
        const float d = dist_s[e];
        const float t = d - (7.0f / 63.0f) * (float)k;
        const float rbf = __expf(-40.5f * t * t);
        const float env = (d < 7.0f) ? (0.5f * (__cosf(d * (3.14159265358979f / 7.0f)) + 1.0f)) : 0.0f;
        const int ktl = k >> 5, kg = (k >> 3) & 3, jj = k & 7, half = e >> 4, row = e & 15;
        dembF[((ktl * 2 + half) * 64 + kg * 16 + row) * 8 + jj] = f2b(rbf * env);
    }
    __syncthreads();

    const char* pA = (const char*)Pf + lane * 16;     // fragment-linear A reads
    const short8* WT8 = (const short8*)wsp;
    const int bcol = wave * 64 + lane;

    f32x4 acc0 = {0.f, 0.f, 0.f, 0.f}, acc1 = {0.f, 0.f, 0.f, 0.f};

    // ---- TP chunk A: k 0..511 (l0, u 0..15) ----
    build_l0_frag(Pf, x1, x2, tid, 0);
    __syncthreads();
#pragma unroll 4
    for (int kt = 0; kt < 16; ++kt) {
        const short8 a0 = *(const short8*)(pA + kt * 2048);
        const short8 a1 = *(const short8*)(pA + kt * 2048 + 1024);
        const short8 b = WT8[kt * 512 + bcol];
        acc0 = __builtin_amdgcn_mfma_f32_16x16x32_bf16(a0, b, acc0, 0, 0, 0);
        acc1 = __builtin_amdgcn_mfma_f32_16x16x32_bf16(a1, b, acc1, 0, 0, 0);
    }
    __syncthreads();

    // ---- TP chunk B: k 512..1023 (l0, u 16..31) ----
    build_l0_frag(Pf, x1, x2, tid, 16);
    __syncthreads();
#pragma unroll 4
    for (int kt = 0; kt < 16; ++kt) {
        const short8 a0 = *(const short8*)(pA + kt * 2048);
        const short8 a1 = *(const short8*)(pA + kt * 2048 + 1024);
        const short8 b = WT8[(16 + kt) * 512 + bcol];
        acc0 = __builtin_amdgcn_mfma_f32_16x16x32_bf16(a0, b, acc0, 0, 0, 0);
        acc1 = __builtin_amdgcn_mfma_f32_16x16x32_bf16(a1, b, acc1, 0, 0, 0);
    }
    __syncthreads();

    // ---- TP chunk C build: k 1024..1343 (l1 kt 0..7, l2 kt 8..9), fragment-linear ----
    {
        const int er = tid & 15, kg = (tid >> 4) & 3, w = tid >> 6;
        // l1: wave w owns ktl = w; u1 = 2w + (kg>>1), v1 = (kg&1)*8 + jj
        const int u1 = 2 * w + (kg >> 1);
        const int vb = (kg & 1) * 8;
#pragma unroll
        for (int half = 0; half < 2; ++half) {
            const int e = half * 16 + er;
            const float* b1p = x1 + e * XSTR + 32 + 3 * u1;
            const float b1a = b1p[0], b1b = b1p[1], b1c = b1p[2];
            const float* b2b = x2 + e * XSTR + 32 + 3 * vb;
            float pr[8];
#pragma unroll
            for (int jj = 0; jj < 8; ++jj) {
                const float* b2p = b2b + 3 * jj;
                pr[jj] = b1a * b2p[0] + b1b * b2p[1] + b1c * b2p[2];
            }
            uint4 o;
            o.x = f2b2(pr[0], pr[1]); o.y = f2b2(pr[2], pr[3]);
            o.z = f2b2(pr[4], pr[5]); o.w = f2b2(pr[6], pr[7]);
            *(uint4*)(Pf + ((w * 2 + half) * 64 + lane) * 8) = o;
        }
        // l2: waves 0..3, ktl = 8 + (w>>1), half = w&1; u2 = (ktl-8)*4 + kg, v2 = jj
        if (w < 4) {
            const int half = w & 1;
            const int ktl = 8 + (w >> 1);
            const int u2 = (ktl - 8) * 4 + kg;
            const int e = half * 16 + er;
            const float* c1p = x1 + e * XSTR + 80 + 5 * u2;
            const float c1a = c1p[0], c1b = c1p[1], c1c = c1p[2], c1d = c1p[3], c1e = c1p[4];
            float pr[8];
#pragma unroll
            for (int jj = 0; jj < 8; ++jj) {
                const float* c2p = x2 + e * XSTR + 80 + 5 * jj;
                pr[jj] = c1a * c2p[0] + c1b * c2p[1] + c1c * c2p[2] + c1d * c2p[3] + c1e * c2p[4];
            }
            uint4 o;
            o.x = f2b2(pr[0], pr[1]); o.y = f2b2(pr[2], pr[3]);
            o.z = f2b2(pr[4], pr[5]); o.w = f2b2(pr[6], pr[7]);
            *(uint4*)(Pf + ((ktl * 2 + half) * 64 + lane) * 8) = o;
        }
    }
    __syncthreads();

    // ---- TP chunk C gemm + filter GEMM1 (x region dead -> h1F alias OK) ----
#pragma unroll 2
    for (int kt = 0; kt < 10; ++kt) {
        const short8 a0 = *(const short8*)(pA + kt * 2048);
        const short8 a1 = *(const short8*)(pA + kt * 2048 + 1024);
        const short8 b = WT8[(32 + kt) * 512 + bcol];
        acc0 = __builtin_amdgcn_mfma_f32_16x16x32_bf16(a0, b, acc0, 0, 0, 0);
        acc1 = __builtin_amdgcn_mfma_f32_16x16x32_bf16(a1, b, acc1, 0, 0, 0);
    }
    {
        f32x4 f0 = {0.f, 0.f, 0.f, 0.f}, f1 = {0.f, 0.f, 0.f, 0.f};
        const char* dA = (const char*)dembF + lane * 16;
#pragma unroll
        for (int kt = 0; kt < 2; ++kt) {
            const short8 a0 = *(const short8*)(dA + kt * 2048);
            const short8 a1 = *(const short8*)(dA + kt * 2048 + 1024);
            const short8 b = WT8[WS_WF1 / 8 + kt * 512 + bcol];
            f0 = __builtin_amdgcn_mfma_f32_16x16x32_bf16(a0, b, f0, 0, 0, 0);
            f1 = __builtin_amdgcn_mfma_f32_16x16x32_bf16(a1, b, f1, 0, 0, 0);
        }
        const int n = wave * 16 + lr;
        const float bb = df_b1[n];
        const int ktl = n >> 5, kg2 = (n >> 3) & 3, jj = n & 7;
#pragma unroll
        for (int r = 0; r < 4; ++r) {
            const int row = lg * 4 + r;
            h1F[((ktl * 2 + 0) * 64 + kg2 * 16 + row) * 8 + jj] = f2b(silu_f(f0[r] + bb));
            h1F[((ktl * 2 + 1) * 64 + kg2 * 16 + row) * 8 + jj] = f2b(silu_f(f1[r] + bb));
        }
    }
    __syncthreads();

    // ---- filter GEMM2 -> dfilter (regs) + LN partials ----
    f32x4 d0 = {0.f, 0.f, 0.f, 0.f}, d1 = {0.f, 0.f, 0.f, 0.f};
    {
        const char* hA = (const char*)h1F + lane * 16;
#pragma unroll
        for (int kt = 0; kt < 4; ++kt) {
            const short8 a0 = *(const short8*)(hA + kt * 2048);
            const short8 a1 = *(const short8*)(hA + kt * 2048 + 1024);
            const short8 b = WT8[WS_WF2 / 8 + kt * 512 + bcol];
            d0 = __builtin_amdgcn_mfma_f32_16x16x32_bf16(a0, b, d0, 0, 0, 0);
            d1 = __builtin_amdgcn_mfma_f32_16x16x32_bf16(a1, b, d1, 0, 0, 0);
        }
        const int n = wave * 16 + lr;
        const float b2v = df_b2[n];
#pragma unroll
        for (int r = 0; r < 4; ++r) { d0[r] += b2v; d1[r] += b2v; }
    }
#pragma unroll
    for (int mt = 0; mt < 2; ++mt) {
#pragma unroll
        for (int r = 0; r < 4; ++r) {
            const float v = mt ? acc1[r] : acc0[r];
            float s1 = v, s2 = v * v;
            s1 += __shfl_xor(s1, 1);  s2 += __shfl_xor(s2, 1);
            s1 += __shfl_xor(s1, 2);  s2 += __shfl_xor(s2, 2);
            s1 += __shfl_xor(s1, 4);  s2 += __shfl_xor(s2, 4);
            s1 += __shfl_xor(s1, 8);  s2 += __shfl_xor(s2, 8);
            if (lr == 0) {
                const int idx = ((wave * 2 + mt) * 4 + lg) * 4 + r;
                red1[idx] = s1;
                red1[256 + idx] = s2;
            }
        }
    }
    __syncthreads();
    if (tid < ET) {
        const int mt = tid >> 4, g = (tid >> 2) & 3, r = tid & 3;
        float s1 = 0.f, s2 = 0.f;
#pragma unroll
        for (int w = 0; w < 8; ++w) {
            const int idx = ((w * 2 + mt) * 4 + g) * 4 + r;
            s1 += red1[idx];
            s2 += red1[256 + idx];
        }
        const float mu = s1 * (1.0f / 128.0f);
        const float var = s2 * (1.0f / 128.0f) - mu * mu;
        mu_s[tid] = mu;
        rstd_s[tid] = rsqrtf(var + 1e-5f);
    }
    __syncthreads();

    // ---- regulated -> regF (fragment-linear bf16) ----
    {
        const int n = wave * 16 + lr;
        const float gv = ln_g[n], bv = ln_b[n];
        const int ktl = n >> 5, kg2 = (n >> 3) & 3, jj = n & 7;
#pragma unroll
        for (int mt = 0; mt < 2; ++mt) {
#pragma unroll
            for (int r = 0; r < 4; ++r) {
                const int row = lg * 4 + r;
                const float v = mt ? acc1[r] : acc0[r];
                const float ln = (v - mu_s[mt * 16 + row]) * rstd_s[mt * 16 + row] * gv + bv;
                const float df = mt ? d1[r] : d0[r];
                regF[((ktl * 2 + mt) * 64 + kg2 * 16 + row) * 8 + jj] = f2b(ln * df);
            }
        }
    }
    __syncthreads();

    // ---- MLP: out = silu(reg @ w1 + b1) @ w2 + b2 ----
    {
        f32x4 m00 = {0.f,0.f,0.f,0.f}, m01 = {0.f,0.f,0.f,0.f};
        f32x4 m10 = {0.f,0.f,0.f,0.f}, m11 = {0.f,0.f,0.f,0.f};
        f32x4 m20 = {0.f,0.f,0.f,0.f}, m21 = {0.f,0.f,0.f,0.f};
        f32x4 m30 = {0.f,0.f,0.f,0.f}, m31 = {0.f,0.f,0.f,0.f};
        const char* rA = (const char*)regF + lane * 16;
#pragma unroll
        for (int kt = 0; kt < 4; ++kt) {
            const short8 a0 = *(const short8*)(rA + kt * 2048);
            const short8 a1 = *(const short8*)(rA + kt * 2048 + 1024);
            const int base = WS_WM1 / 8 + kt * 2048 + wave * 256 + lane;
            const short8 b0 = WT8[base];
            const short8 b1 = WT8[base + 64];
            const short8 b2 = WT8[base + 128];
            const short8 b3 = WT8[base + 192];
            m00 = __builtin_amdgcn_mfma_f32_16x16x32_bf16(a0, b0, m00, 0, 0, 0);
            m01 = __builtin_amdgcn_mfma_f32_16x16x32_bf16(a1, b0, m01, 0, 0, 0);
            m10 = __builtin_amdgcn_mfma_f32_16x16x32_bf16(a0, b1, m10, 0, 0, 0);
            m11 = __builtin_amdgcn_mfma_f32_16x16x32_bf16(a1, b1, m11, 0, 0, 0);
            m20 = __builtin_amdgcn_mfma_f32_16x16x32_bf16(a0, b2, m20, 0, 0, 0);
            m21 = __builtin_amdgcn_mfma_f32_16x16x32_bf16(a1, b2, m21, 0, 0, 0);
            m30 = __builtin_amdgcn_mfma_f32_16x16x32_bf16(a0, b3, m30, 0, 0, 0);
            m31 = __builtin_amdgcn_mfma_f32_16x16x32_bf16(a1, b3, m31, 0, 0, 0);
        }
        float po0[4] = {0.f,0.f,0.f,0.f}, po1[4] = {0.f,0.f,0.f,0.f};
#pragma unroll
        for (int q = 0; q < 4; ++q) {
            const int n = (wave * 4 + q) * 16 + lr;
            const float b1v = mlp_b1[n];
            const float w2v = mlp_w2[n];
            const f32x4 h0 = (q == 0) ? m00 : (q == 1) ? m10 : (q == 2) ? m20 : m30;
            const f32x4 h1v = (q == 0) ? m01 : (q == 1) ? m11 : (q == 2) ? m21 : m31;
#pragma unroll
            for (int r = 0; r < 4; ++r) {
                po0[r] += silu_f(h0[r] + b1v) * w2v;
                po1[r] += silu_f(h1v[r] + b1v) * w2v;
            }
        }
#pragma unroll
        for (int r = 0; r < 4; ++r) {
            float a = po0[r], b = po1[r];
            a += __shfl_xor(a, 1); b += __shfl_xor(b, 1);
            a += __shfl_xor(a, 2); b += __shfl_xor(b, 2);
            a += __shfl_xor(a, 4); b += __shfl_xor(b, 4);
            a += __shfl_xor(a, 8); b += __shfl_xor(b, 8);
            if (lr == 0) {
                red2[((wave * 2 + 0) * 4 + lg) * 4 + r] = a;
                red2[((wave * 2 + 1) * 4 + lg) * 4 + r] = b;
            }
        }
    }
    __syncthreads();
    if (tid < ET) {
        const int mt = tid >> 4, g = (tid >> 2) & 3, r = tid & 3;
        float s = 0.f;
#pragma unroll
        for (int w = 0; w < 8; ++w)
            s += red2[((w * 2 + mt) * 4 + g) * 4 + r];
        out[e0g + tid] = s + mlp_b2[0];
    }
}

extern "C" void kernel_launch(void* const* d_in, const int* in_sizes, int n_in,
                              void* d_out, int out_size, void* d_ws, size_t ws_size,
                              hipStream_t stream) {
    const float* nodes      = (const float*)d_in[0];
    const int*   edge_index = (const int*)  d_in[1];
    const int*   graph_b    = (const int*)  d_in[2];
    const float* cell       = (const float*)d_in[3];
    const float* edge_shift = (const float*)d_in[4];
    const float* pos        = (const float*)d_in[5];
    const float* W0         = (const float*)d_in[6];
    const float* W1         = (const float*)d_in[7];
    const float* W2         = (const float*)d_in[8];
    const float* ln_g       = (const float*)d_in[9];
    const float* ln_b       = (const float*)d_in[10];
    const float* df_w1      = (const float*)d_in[11];
    const float* df_b1      = (const float*)d_in[12];
    const float* df_w2      = (const float*)d_in[13];
    const float* df_b2      = (const float*)d_in[14];
    const float* mlp_w1     = (const float*)d_in[15];
    const float* mlp_b1     = (const float*)d_in[16];
    const float* mlp_w2     = (const float*)d_in[17];
    const float* mlp_b2     = (const float*)d_in[18];
    float* out = (float*)d_out;
    ushort_t* ws = (ushort_t*)d_ws;

    hipLaunchKernelGGL(prep_weights, dim3((WS_TOTAL + 255) / 256), dim3(256), 0, stream,
                       W0, W1, W2, df_w1, df_w2, mlp_w1, ws);

    const int E = in_sizes[1] / 2;
    const int grid = E / ET;   // 12500
    hipLaunchKernelGGL(fused_edge_kernel, dim3(grid), dim3(NTHR), 0, stream,
                       nodes, edge_index, graph_b, cell, edge_shift, pos,
                       ln_g, ln_b, df_b1, df_b2, mlp_b1, mlp_w2, mlp_b2,
                       ws, out);
}

// Round 4
// 458.196 us; speedup vs baseline: 10.6084x; 1.1117x over previous
//
#include <hip/hip_runtime.h>
#include <hip/hip_bf16.h>
#include <math.h>

typedef unsigned short ushort_t;
typedef short short8 __attribute__((ext_vector_type(8)));
typedef float f32x4 __attribute__((ext_vector_type(4)));

#define E_TOTAL 400000
#define ET 64          // edges per block
#define NTHR 512       // 8 waves
#define NODE_D 120
#define ASTR 36        // fp32 a-part LDS stride (144 B rows, 16B-aligned)
#define BCSTR 92       // fp32 b/c-part LDS stride (368 B rows, 16B-aligned)

#define ALPHA 0.0272772362793f   // 1/sqrt(1344)
#define S_L1  0.57735026918962f  // 1/sqrt(3)
#define S_L2  0.44721359549996f  // 1/sqrt(5)

// ws layout (ushort elements): TP W-frags [0,172032), df_w1 [172032,180224),
// df_w2 [180224,196608), mlp_w1 [196608,262144).  B-frag order:
// idx = ((kt*NT + nt)*64 + lane)*8 + jj  with k = kt*32 + 8*(lane>>4) + jj,
// n = nt*16 + (lane&15).
#define WS_WF1 172032
#define WS_WF2 180224
#define WS_WM1 196608
#define WS_TOTAL 262144

__device__ __forceinline__ ushort_t f2b(float f) {
    unsigned int b = __float_as_uint(f);
    b += 0x7FFFu + ((b >> 16) & 1u);   // RNE
    return (ushort_t)(b >> 16);
}
__device__ __forceinline__ unsigned int f2b2(float a, float b) {
    __hip_bfloat162 h = __float22bfloat162_rn(make_float2(a, b));  // v_cvt_pk_bf16_f32
    union { __hip_bfloat162 h2; unsigned int u; } cv; cv.h2 = h;
    return cv.u;
}
__device__ __forceinline__ float silu_f(float x) { return x / (1.0f + __expf(-x)); }

__global__ __launch_bounds__(256) void prep_weights(
    const float* __restrict__ W0, const float* __restrict__ W1, const float* __restrict__ W2,
    const float* __restrict__ df_w1, const float* __restrict__ df_w2,
    const float* __restrict__ mlp_w1, ushort_t* __restrict__ ws)
{
    const int i = blockIdx.x * 256 + threadIdx.x;
    if (i >= WS_TOTAL) return;
    float v;
    if (i < WS_WF1) {            // TP: 42 kt x 8 nt
        const int r = i;
        const int kt = r >> 12, nt = (r >> 9) & 7, l = (r >> 3) & 63, jj = r & 7;
        const int k = kt * 32 + ((l >> 4) << 3) + jj;
        const int n = nt * 16 + (l & 15);
        if (k < 1024)      v = W0[k * 128 + n] * ALPHA;
        else if (k < 1280) v = W1[(k - 1024) * 128 + n] * (ALPHA * S_L1);
        else               v = W2[(k - 1280) * 128 + n] * (ALPHA * S_L2);
    } else if (i < WS_WF2) {     // df_w1: 2 kt x 8 nt
        const int r = i - WS_WF1;
        const int kt = r >> 12, nt = (r >> 9) & 7, l = (r >> 3) & 63, jj = r & 7;
        v = df_w1[(kt * 32 + ((l >> 4) << 3) + jj) * 128 + nt * 16 + (l & 15)];
    } else if (i < WS_WM1) {     // df_w2: 4 kt x 8 nt
        const int r = i - WS_WF2;
        const int kt = r >> 12, nt = (r >> 9) & 7, l = (r >> 3) & 63, jj = r & 7;
        v = df_w2[(kt * 32 + ((l >> 4) << 3) + jj) * 128 + nt * 16 + (l & 15)];
    } else {                     // mlp_w1: 4 kt x 32 nt
        const int r = i - WS_WM1;
        const int kt = r >> 14, nt = (r >> 9) & 31, l = (r >> 3) & 63, jj = r & 7;
        v = mlp_w1[(kt * 32 + ((l >> 4) << 3) + jj) * 512 + nt * 16 + (l & 15)];
    }
    ws[i] = f2b(v);
}

__global__ __launch_bounds__(NTHR, 4) void fused_edge_kernel(
    const float* __restrict__ nodes, const int* __restrict__ edge_index,
    const int* __restrict__ graph_batch, const float* __restrict__ cell,
    const float* __restrict__ edge_shift, const float* __restrict__ pos,
    const float* __restrict__ ln_g, const float* __restrict__ ln_b,
    const float* __restrict__ df_b1, const float* __restrict__ df_b2,
    const float* __restrict__ mlp_b1, const float* __restrict__ mlp_w2,
    const float* __restrict__ mlp_b2,
    const ushort_t* __restrict__ wsp, float* __restrict__ out)
{
    // Pf: 8-kt A-fragment chunk buffer, 8 kt x 4 halves x 64 lanes x 8 us = 32 KB.
    __shared__ __align__(16) ushort_t Pf[8 * 4 * 64 * 8];
    // X region, 47104 B, time-multiplexed:
    //  l0 phase:   xa1 [0,9216) xa2 [9216,18432)  (64 x 36 fp32 each)
    //  l1/l2:      bc1 [0,23552) bc2 [23552,47104) (64 x 92 fp32 each)
    //  post-TP:    h1F [0,16384) regF [16384,32768) red1 [32768,36864) red2 [36864,38912)
    __shared__ __align__(16) char Xb[47104];
    __shared__ float dist_s[ET];
    __shared__ int sidx[ET], didx[ET];
    __shared__ float mu_s[ET], rstd_s[ET];

    float* xa1 = (float*)Xb;
    float* xa2 = xa1 + ET * ASTR;
    float* bc1 = (float*)Xb;
    float* bc2 = bc1 + ET * BCSTR;
    ushort_t* h1F  = (ushort_t*)Xb;
    ushort_t* regF = h1F + 8192;
    float* red1 = (float*)(Xb + 32768);
    float* red2 = (float*)(Xb + 36864);
    ushort_t* dembF = Pf + 4096;   // kt 2..3 slots of Pf (not read by l2 gemm)

    const int tid = threadIdx.x;
    const int e0g = blockIdx.x * ET;
    const int wave = tid >> 6, lane = tid & 63;
    const int lr = lane & 15, lg = lane >> 4;
    const int er = tid & 15, kg = (tid >> 4) & 3, w = tid >> 6;

    // ---- phase 0: geometry ----
    if (tid < ET) {
        const int e = e0g + tid;
        const int s = edge_index[e];
        const int d = edge_index[E_TOTAL + e];
        sidx[tid] = s; didx[tid] = d;
        const int g = graph_batch[s];
        const float* c = cell + g * 9;
        const float sx = edge_shift[e * 3], sy = edge_shift[e * 3 + 1], sz = edge_shift[e * 3 + 2];
        const float t0 = sx * c[0] + sy * c[3] + sz * c[6];
        const float t1 = sx * c[1] + sy * c[4] + sz * c[7];
        const float t2 = sx * c[2] + sy * c[5] + sz * c[8];
        const float r0 = pos[d * 3 + 0] - pos[s * 3 + 0] + t0;
        const float r1 = pos[d * 3 + 1] - pos[s * 3 + 1] + t1;
        const float r2 = pos[d * 3 + 2] - pos[s * 3 + 2] + t2;
        dist_s[tid] = sqrtf(r0 * r0 + r1 * r1 + r2 * r2);
    }
    __syncthreads();

    // ---- phase 1: gather a-parts (first 32 floats of each node row) ----
    {
        const int e = tid >> 3, c = tid & 7;   // exactly 512 slots
        *(float4*)(xa1 + e * ASTR + c * 4) = *(const float4*)(nodes + (size_t)sidx[e] * NODE_D + c * 4);
        *(float4*)(xa2 + e * ASTR + c * 4) = *(const float4*)(nodes + (size_t)didx[e] * NODE_D + c * 4);
    }
    __syncthreads();

    const char* pA = (const char*)Pf + lane * 16;
    const short8* WT8 = (const short8*)wsp;
    const int bcol = tid;   // = wave*64 + lane; wave == n-tile

    f32x4 acc[4] = {{0.f,0.f,0.f,0.f},{0.f,0.f,0.f,0.f},{0.f,0.f,0.f,0.f},{0.f,0.f,0.f,0.f}};

    // hoist a2 (8 floats per half) into registers — reused across all 4 l0 chunks
    float2 a2v[4][4];
#pragma unroll
    for (int h = 0; h < 4; ++h)
#pragma unroll
        for (int q = 0; q < 4; ++q)
            a2v[h][q] = *(const float2*)(xa2 + (h * 16 + er) * ASTR + kg * 8 + q * 2);

    // ---- TP l0: 4 chunks of u-range 8 (K = 4 x 256) ----
#pragma unroll 1
    for (int c4 = 0; c4 < 4; ++c4) {
#pragma unroll
        for (int h = 0; h < 4; ++h) {
            const float a1 = xa1[(h * 16 + er) * ASTR + c4 * 8 + w];
            uint4 o;
            o.x = f2b2(a1 * a2v[h][0].x, a1 * a2v[h][0].y);
            o.y = f2b2(a1 * a2v[h][1].x, a1 * a2v[h][1].y);
            o.z = f2b2(a1 * a2v[h][2].x, a1 * a2v[h][2].y);
            o.w = f2b2(a1 * a2v[h][3].x, a1 * a2v[h][3].y);
            *(uint4*)(Pf + ((w * 4 + h) * 64 + kg * 16 + er) * 8) = o;
        }
        __syncthreads();
#pragma unroll 2
        for (int kt = 0; kt < 8; ++kt) {
            const short8 b = WT8[(c4 * 8 + kt) * 512 + bcol];
#pragma unroll
            for (int h = 0; h < 4; ++h) {
                const short8 a = *(const short8*)(pA + (kt * 4 + h) * 1024);
                acc[h] = __builtin_amdgcn_mfma_f32_16x16x32_bf16(a, b, acc[h], 0, 0, 0);
            }
        }
        if (c4 == 3) {
            // gather b/c parts (floats 32..119) — overlapped with last l0 gemm
            for (int i = tid; i < ET * 22; i += NTHR) {
                const int e = i / 22, c = i % 22;
                *(float4*)(bc1 + e * BCSTR + c * 4) =
                    *(const float4*)(nodes + (size_t)sidx[e] * NODE_D + 32 + c * 4);
            }
            for (int i = tid; i < ET * 22; i += NTHR) {
                const int e = i / 22, c = i % 22;
                *(float4*)(bc2 + e * BCSTR + c * 4) =
                    *(const float4*)(nodes + (size_t)didx[e] * NODE_D + 32 + c * 4);
            }
        }
        __syncthreads();
    }

    // ---- TP l1 build (8 kt, K=256) ----
    {
        const int u1 = 2 * w + (kg >> 1);
        const int vb = (kg & 1) * 8;
#pragma unroll
        for (int h = 0; h < 4; ++h) {
            const int e = h * 16 + er;
            const float* b1p = bc1 + e * BCSTR + 3 * u1;
            const float b1a = b1p[0], b1b = b1p[1], b1c = b1p[2];
            const float* b2b = bc2 + e * BCSTR + 3 * vb;
            float pr[8];
#pragma unroll
            for (int jj = 0; jj < 8; ++jj) {
                const float* b2p = b2b + 3 * jj;
                pr[jj] = b1a * b2p[0] + b1b * b2p[1] + b1c * b2p[2];
            }
            uint4 o;
            o.x = f2b2(pr[0], pr[1]); o.y = f2b2(pr[2], pr[3]);
            o.z = f2b2(pr[4], pr[5]); o.w = f2b2(pr[6], pr[7]);
            *(uint4*)(Pf + ((w * 4 + h) * 64 + kg * 16 + er) * 8) = o;
        }
    }
    __syncthreads();
#pragma unroll 2
    for (int kt = 0; kt < 8; ++kt) {
        const short8 b = WT8[(32 + kt) * 512 + bcol];
#pragma unroll
        for (int h = 0; h < 4; ++h) {
            const short8 a = *(const short8*)(pA + (kt * 4 + h) * 1024);
            acc[h] = __builtin_amdgcn_mfma_f32_16x16x32_bf16(a, b, acc[h], 0, 0, 0);
        }
    }
    __syncthreads();

    // ---- TP l2 build (2 kt, K=64): one Pf slot per thread ----
    {
        const int ktl = w >> 2, h2 = w & 3;
        const int u2 = ktl * 4 + kg;
        const int e = h2 * 16 + er;
        const float* c1p = bc1 + e * BCSTR + 48 + 5 * u2;
        const float c1a = c1p[0], c1b = c1p[1], c1c = c1p[2], c1d = c1p[3], c1e = c1p[4];
        float pr[8];
#pragma unroll
        for (int jj = 0; jj < 8; ++jj) {
            const float* c2p = bc2 + e * BCSTR + 48 + 5 * jj;
            pr[jj] = c1a * c2p[0] + c1b * c2p[1] + c1c * c2p[2] + c1d * c2p[3] + c1e * c2p[4];
        }
        uint4 o;
        o.x = f2b2(pr[0], pr[1]); o.y = f2b2(pr[2], pr[3]);
        o.z = f2b2(pr[4], pr[5]); o.w = f2b2(pr[6], pr[7]);
        *(uint4*)(Pf + ((ktl * 4 + h2) * 64 + kg * 16 + er) * 8) = o;
    }
    __syncthreads();
#pragma unroll
    for (int kt = 0; kt < 2; ++kt) {
        const short8 b = WT8[(40 + kt) * 512 + bcol];
#pragma unroll
        for (int h = 0; h < 4; ++h) {
            const short8 a = *(const short8*)(pA + (kt * 4 + h) * 1024);
            acc[h] = __builtin_amdgcn_mfma_f32_16x16x32_bf16(a, b, acc[h], 0, 0, 0);
        }
    }
    // demb build into Pf kt2..3 region (not read by l2 gemm) — overlapped
    for (int i = tid; i < ET * 64; i += NTHR) {
        const int e = i >> 6, k = i & 63;
        const float d = dist_s[e];
        const float t = d - (7.0f / 63.0f) * (float)k;
        const float rbf = __expf(-40.5f * t * t);
        const float env = (d < 7.0f) ? (0.5f * (__cosf(d * (3.14159265358979f / 7.0f)) + 1.0f)) : 0.0f;
        const int ktl = k >> 5, kgd = (k >> 3) & 3, jj = k & 7, half = e >> 4, row = e & 15;
        dembF[((ktl * 4 + half) * 64 + kgd * 16 + row) * 8 + jj] = f2b(rbf * env);
    }
    __syncthreads();

    // ---- filter GEMM1: h1 = silu(demb @ df_w1 + b1) -> h1F (bc region dead) ----
    {
        f32x4 f[4] = {{0.f,0.f,0.f,0.f},{0.f,0.f,0.f,0.f},{0.f,0.f,0.f,0.f},{0.f,0.f,0.f,0.f}};
        const char* dA = (const char*)dembF + lane * 16;
#pragma unroll
        for (int kt = 0; kt < 2; ++kt) {
            const short8 b = WT8[WS_WF1 / 8 + kt * 512 + bcol];
#pragma unroll
            for (int h = 0; h < 4; ++h) {
                const short8 a = *(const short8*)(dA + (kt * 4 + h) * 1024);
                f[h] = __builtin_amdgcn_mfma_f32_16x16x32_bf16(a, b, f[h], 0, 0, 0);
            }
        }
        const int n = wave * 16 + lr;
        const float bb = df_b1[n];
        const int ktl = n >> 5, kg2 = (n >> 3) & 3, jjn = n & 7;
#pragma unroll
        for (int h = 0; h < 4; ++h)
#pragma unroll
            for (int r = 0; r < 4; ++r)
                h1F[((ktl * 4 + h) * 64 + kg2 * 16 + lg * 4 + r) * 8 + jjn] = f2b(silu_f(f[h][r] + bb));
    }
    __syncthreads();

    // ---- filter GEMM2 -> dfilter regs + LN partials ----
    f32x4 d[4] = {{0.f,0.f,0.f,0.f},{0.f,0.f,0.f,0.f},{0.f,0.f,0.f,0.f},{0.f,0.f,0.f,0.f}};
    {
        const char* hA = (const char*)h1F + lane * 16;
#pragma unroll
        for (int kt = 0; kt < 4; ++kt) {
            const short8 b = WT8[WS_WF2 / 8 + kt * 512 + bcol];
#pragma unroll
            for (int h = 0; h < 4; ++h) {
                const short8 a = *(const short8*)(hA + (kt * 4 + h) * 1024);
                d[h] = __builtin_amdgcn_mfma_f32_16x16x32_bf16(a, b, d[h], 0, 0, 0);
            }
        }
        const int n = wave * 16 + lr;
        const float b2v = df_b2[n];
#pragma unroll
        for (int h = 0; h < 4; ++h)
#pragma unroll
            for (int r = 0; r < 4; ++r) d[h][r] += b2v;
    }
#pragma unroll
    for (int h = 0; h < 4; ++h) {
#pragma unroll
        for (int r = 0; r < 4; ++r) {
            const float v = acc[h][r];
            float s1 = v, s2 = v * v;
            s1 += __shfl_xor(s1, 1);  s2 += __shfl_xor(s2, 1);
            s1 += __shfl_xor(s1, 2);  s2 += __shfl_xor(s2, 2);
            s1 += __shfl_xor(s1, 4);  s2 += __shfl_xor(s2, 4);
            s1 += __shfl_xor(s1, 8);  s2 += __shfl_xor(s2, 8);
            if (lr == 0) {
                const int idx = ((wave * 4 + h) * 4 + lg) * 4 + r;
                red1[idx] = s1;
                red1[512 + idx] = s2;
            }
        }
    }
    __syncthreads();
    if (tid < ET) {
        const int h = tid >> 4, g = (tid >> 2) & 3, r = tid & 3;
        float s1 = 0.f, s2 = 0.f;
#pragma unroll
        for (int ww = 0; ww < 8; ++ww) {
            const int idx = ((ww * 4 + h) * 4 + g) * 4 + r;
            s1 += red1[idx];
            s2 += red1[512 + idx];
        }
        const float mu = s1 * (1.0f / 128.0f);
        const float var = s2 * (1.0f / 128.0f) - mu * mu;
        mu_s[tid] = mu;
        rstd_s[tid] = rsqrtf(var + 1e-5f);
    }
    __syncthreads();

    // ---- regulated -> regF (fragment-linear bf16) ----
    {
        const int n = wave * 16 + lr;
        const float gv = ln_g[n], bv = ln_b[n];
        const int ktl = n >> 5, kg2 = (n >> 3) & 3, jjn = n & 7;
#pragma unroll
        for (int h = 0; h < 4; ++h) {
#pragma unroll
            for (int r = 0; r < 4; ++r) {
                const int row = lg * 4 + r, e = h * 16 + row;
                const float ln = (acc[h][r] - mu_s[e]) * rstd_s[e] * gv + bv;
                regF[((ktl * 4 + h) * 64 + kg2 * 16 + row) * 8 + jjn] = f2b(ln * d[h][r]);
            }
        }
    }
    __syncthreads();

    // ---- MLP: out = silu(reg @ w1 + b1) @ w2 + b2 ----
    {
        f32x4 m[4][4];   // [nt q][half h]
#pragma unroll
        for (int q = 0; q < 4; ++q)
#pragma unroll
            for (int h = 0; h < 4; ++h) m[q][h] = (f32x4){0.f,0.f,0.f,0.f};
        const char* rA = (const char*)regF + lane * 16;
#pragma unroll
        for (int kt = 0; kt < 4; ++kt) {
            short8 a[4];
#pragma unroll
            for (int h = 0; h < 4; ++h)
                a[h] = *(const short8*)(rA + (kt * 4 + h) * 1024);
            const int base = WS_WM1 / 8 + kt * 2048 + wave * 256 + lane;
#pragma unroll
            for (int q = 0; q < 4; ++q) {
                const short8 b = WT8[base + q * 64];
#pragma unroll
                for (int h = 0; h < 4; ++h)
                    m[q][h] = __builtin_amdgcn_mfma_f32_16x16x32_bf16(a[h], b, m[q][h], 0, 0, 0);
            }
        }
        float po[4][4];
#pragma unroll
        for (int h = 0; h < 4; ++h)
#pragma unroll
            for (int r = 0; r < 4; ++r) po[h][r] = 0.f;
#pragma unroll
        for (int q = 0; q < 4; ++q) {
            const int n = (wave * 4 + q) * 16 + lr;
            const float b1v = mlp_b1[n];
            const float w2v = mlp_w2[n];
#pragma unroll
            for (int h = 0; h < 4; ++h)
#pragma unroll
                for (int r = 0; r < 4; ++r)
                    po[h][r] += silu_f(m[q][h][r] + b1v) * w2v;
        }
#pragma unroll
        for (int h = 0; h < 4; ++h) {
#pragma unroll
            for (int r = 0; r < 4; ++r) {
                float a = po[h][r];
                a += __shfl_xor(a, 1);
                a += __shfl_xor(a, 2);
                a += __shfl_xor(a, 4);
                a += __shfl_xor(a, 8);
                if (lr == 0) red2[((wave * 4 + h) * 4 + lg) * 4 + r] = a;
            }
        }
    }
    __syncthreads();
    if (tid < ET) {
        const int h = tid >> 4, g = (tid >> 2) & 3, r = tid & 3;
        float s = 0.f;
#pragma unroll
        for (int ww = 0; ww < 8; ++ww)
            s += red2[((ww * 4 + h) * 4 + g) * 4 + r];
        out[e0g + tid] = s + mlp_b2[0];
    }
}

extern "C" void kernel_launch(void* const* d_in, const int* in_sizes, int n_in,
                              void* d_out, int out_size, void* d_ws, size_t ws_size,
                              hipStream_t stream) {
    const float* nodes      = (const float*)d_in[0];
    const int*   edge_index = (const int*)  d_in[1];
    const int*   graph_b    = (const int*)  d_in[2];
    const float* cell       = (const float*)d_in[3];
    const float* edge_shift = (const float*)d_in[4];
    const float* pos        = (const float*)d_in[5];
    const float* W0         = (const float*)d_in[6];
    const float* W1         = (const float*)d_in[7];
    const float* W2         = (const float*)d_in[8];
    const float* ln_g       = (const float*)d_in[9];
    const float* ln_b       = (const float*)d_in[10];
    const float* df_w1      = (const float*)d_in[11];
    const float* df_b1      = (const float*)d_in[12];
    const float* df_w2      = (const float*)d_in[13];
    const float* df_b2      = (const float*)d_in[14];
    const float* mlp_w1     = (const float*)d_in[15];
    const float* mlp_b1     = (const float*)d_in[16];
    const float* mlp_w2     = (const float*)d_in[17];
    const float* mlp_b2     = (const float*)d_in[18];
    float* out = (float*)d_out;
    ushort_t* ws = (ushort_t*)d_ws;

    hipLaunchKernelGGL(prep_weights, dim3((WS_TOTAL + 255) / 256), dim3(256), 0, stream,
                       W0, W1, W2, df_w1, df_w2, mlp_w1, ws);

    const int E = in_sizes[1] / 2;
    const int grid = E / ET;   // 6250
    hipLaunchKernelGGL(fused_edge_kernel, dim3(grid), dim3(NTHR), 0, stream,
                       nodes, edge_index, graph_b, cell, edge_shift, pos,
                       ln_g, ln_b, df_b1, df_b2, mlp_b1, mlp_w2, mlp_b2,
                       ws, out);
}